// Round 11
// baseline (530.409 us; speedup 1.0000x reference)
//
#include <hip/hip_runtime.h>
#include <math.h>

typedef __attribute__((ext_vector_type(8))) short short8;
typedef __attribute__((ext_vector_type(4))) float floatx4;

#define HDIM 128
#define NPB 256          // nodes per bucket (CSR build)
#define BKMAX 1024       // max buckets (N <= 262144)
#define CHUNK 8192       // edges per pair_scatter block
#define STAGE_CAP 8192   // per-bucket srclist LDS stage (ints)

__device__ __forceinline__ float bf2f(unsigned short u) {
    unsigned int x = ((unsigned int)u) << 16;
    float f;
    __builtin_memcpy(&f, &x, 4);
    return f;
}
__device__ __forceinline__ unsigned short f2bf(float f) {
    unsigned int x;
    __builtin_memcpy(&x, &f, 4);
    unsigned int r = (x + 0x7fffu + ((x >> 16) & 1u)) >> 16;  // RNE
    return (unsigned short)r;
}
// split: hi = truncated bf16 (cheap), lo = RNE bf16 of residual.
__device__ __forceinline__ void split1(float v, unsigned short& hi, unsigned short& lo) {
    unsigned int x;
    __builtin_memcpy(&x, &v, 4);
    hi = (unsigned short)(x >> 16);
    lo = f2bf(v - bf2f(hi));
}
__device__ __forceinline__ float fast_sigmoid(float x) {
    return 1.0f / (1.0f + __expf(-x));
}
__device__ __forceinline__ float fast_tanh(float x) {
    float ax = fabsf(x);
    float e = __expf(2.0f * ax);
    float t = 1.0f - 2.0f / (e + 1.0f);
    return copysignf(t, x);
}

// 16B async global->LDS
__device__ __forceinline__ void gload_lds16(const void* g, void* lds) {
    __builtin_amdgcn_global_load_lds(
        (const __attribute__((address_space(1))) unsigned int*)g,
        (__attribute__((address_space(3))) unsigned int*)lds, 16, 0, 0);
}

// ---------- fused weight prep ----------
// [0,65536) Wih split | [65536,81920) W1^T split | [81920,82432) bsum
__global__ void prep_weights_kernel(const float* __restrict__ Wih,
                                    const float* __restrict__ W1,
                                    const float* __restrict__ bih,
                                    const float* __restrict__ bhh,
                                    unsigned short* __restrict__ Wihh, unsigned short* __restrict__ Wihl,
                                    unsigned short* __restrict__ W1h,  unsigned short* __restrict__ W1l,
                                    float* __restrict__ bsum) {
    int i = blockIdx.x * 256 + threadIdx.x;
    unsigned short h, l;
    if (i < 65536) {
        split1(Wih[i], h, l);
        Wihh[i] = h; Wihl[i] = l;
    } else if (i < 81920) {
        int t = i - 65536, r = t >> 7, c = t & 127;
        split1(W1[r * HDIM + c], h, l);
        W1h[c * HDIM + r] = h; W1l[c * HDIM + r] = l;
    } else if (i < 82432) {
        int t = i - 81920;
        bsum[t] = bih[t] + bhh[t];
    }
}

// ---------- fused W23 = W2 @ W3^T prep (layer-2 GCN x final Linear fusion) ----
// out = relu((A_hat(x1 W2)+b2)W3^T + b3) = relu(A_hat(x1 (W2 W3^T)) + (b2 W3^T + b3))
// B-layout: B[n][k] = sum_p W2[k][p] * W3[n][p].
// [0,16384): W23 split planes; [16384,16512): b23[n] = b3[n] + sum_p b2[p]*W3[n][p]
__global__ void prep_w23_kernel(const float* __restrict__ W2,
                                const float* __restrict__ W3,
                                const float* __restrict__ b2,
                                const float* __restrict__ b3,
                                unsigned short* __restrict__ W23h,
                                unsigned short* __restrict__ W23l,
                                float* __restrict__ b23) {
    int i = blockIdx.x * 256 + threadIdx.x;
    if (i < 16384) {
        int n = i >> 7, k = i & 127;
        float s = 0.0f;
#pragma unroll 8
        for (int p = 0; p < 128; ++p)
            s += W2[k * HDIM + p] * W3[n * HDIM + p];
        unsigned short h, l;
        split1(s, h, l);
        W23h[n * HDIM + k] = h;
        W23l[n * HDIM + k] = l;
    } else if (i < 16512) {
        int n = i - 16384;
        float s = b3[n];
#pragma unroll 8
        for (int p = 0; p < 128; ++p)
            s += b2[p] * W3[n * HDIM + p];
        b23[n] = s;
    }
}

// ================= bucketed CSR build =================
__global__ __launch_bounds__(256)
void bucket_hist_kernel(const int* __restrict__ ei, int* __restrict__ bcnt,
                        long E, int K) {
    __shared__ int h[BKMAX];
    const int tid = threadIdx.x;
    for (int i = tid; i < K; i += 256) h[i] = 0;
    __syncthreads();
    const long base = (long)blockIdx.x * CHUNK;
#pragma unroll
    for (int j = 0; j < CHUNK / 256; ++j) {
        long e = base + j * 256 + tid;
        if (e < E) atomicAdd(&h[((unsigned)ei[E + e]) >> 8], 1);
    }
    __syncthreads();
    for (int i = tid; i < K; i += 256) {
        int c = h[i];
        if (c) atomicAdd(&bcnt[i], c);
    }
}

__global__ __launch_bounds__(1024)
void scan_buckets_kernel(const int* __restrict__ bcnt, int* __restrict__ gbase,
                         int* __restrict__ gcur, int* __restrict__ offs,
                         int K, int N, int Etot) {
    __shared__ int buf[1024];
    const int t = threadIdx.x;
    const int v = (t < K) ? bcnt[t] : 0;
    buf[t] = v;
    __syncthreads();
    for (int off = 1; off < 1024; off <<= 1) {
        int x = buf[t];
        int y = (t >= off) ? buf[t - off] : 0;
        __syncthreads();
        buf[t] = x + y;
        __syncthreads();
    }
    if (t < K) { gbase[t] = buf[t] - v; gcur[t] = buf[t] - v; }
    if (t == 0) { gbase[K] = Etot; offs[N] = Etot; }
}

__global__ __launch_bounds__(256)
void pair_scatter_kernel(const int* __restrict__ ei, int* __restrict__ gcur,
                         unsigned int* __restrict__ pairs, long E, int K) {
    __shared__ int h[BKMAX];
    __shared__ int cur[BKMAX];
    const int tid = threadIdx.x;
    for (int i = tid; i < K; i += 256) h[i] = 0;
    __syncthreads();
    const long base = (long)blockIdx.x * CHUNK;
#pragma unroll
    for (int j = 0; j < CHUNK / 256; ++j) {
        long e = base + j * 256 + tid;
        if (e < E) atomicAdd(&h[((unsigned)ei[E + e]) >> 8], 1);
    }
    __syncthreads();
    for (int i = tid; i < K; i += 256) {
        int c = h[i];
        cur[i] = c ? atomicAdd(&gcur[i], c) : 0;
    }
    __syncthreads();
#pragma unroll
    for (int j = 0; j < CHUNK / 256; ++j) {
        long e = base + j * 256 + tid;
        if (e < E) {
            unsigned int s = (unsigned int)ei[e];
            unsigned int d = (unsigned int)ei[E + e];
            int b = d >> 8;
            int pos = atomicAdd(&cur[b], 1);
            pairs[pos] = s | ((d & (NPB - 1)) << 24);
        }
    }
}

__global__ __launch_bounds__(256)
void bucket_csr_kernel(const unsigned int* __restrict__ pairs, const int* __restrict__ gbase,
                       int* __restrict__ offs, float* __restrict__ dinv,
                       int* __restrict__ srclist, int N) {
    __shared__ int cnt[NPB];
    __shared__ int red[NPB];
    __shared__ int cur[NPB];
    __shared__ int stage[STAGE_CAP];
    const int tid = threadIdx.x;
    const int b = blockIdx.x;
    const int node0 = b << 8;
    const int nn = min(NPB, N - node0);
    const int ebeg = gbase[b];
    const int eend = gbase[b + 1];
    const int ne = eend - ebeg;

    cnt[tid] = 0;
    __syncthreads();
    for (int i = tid; i < ne; i += 256)
        atomicAdd(&cnt[pairs[ebeg + i] >> 24], 1);
    __syncthreads();
    const int myc = cnt[tid];
    red[tid] = myc;
    __syncthreads();
    for (int off = 1; off < NPB; off <<= 1) {
        int x = red[tid];
        int y = (tid >= off) ? red[tid - off] : 0;
        __syncthreads();
        red[tid] = x + y;
        __syncthreads();
    }
    const int loff = red[tid] - myc;   // exclusive
    if (tid < nn) {
        offs[node0 + tid] = ebeg + loff;
        dinv[node0 + tid] = rsqrtf((float)myc + 1.0f);   // +1 self-loop
    }
    cur[tid] = loff;
    __syncthreads();

    if (ne <= STAGE_CAP) {
        for (int i = tid; i < ne; i += 256) {
            unsigned int p = pairs[ebeg + i];
            int pos = atomicAdd(&cur[p >> 24], 1);
            stage[pos] = (int)(p & 0xFFFFFFu);
        }
        __syncthreads();
        for (int i = tid; i < ne; i += 256)
            srclist[ebeg + i] = stage[i];
    } else {
        for (int i = tid; i < ne; i += 256) {
            unsigned int p = pairs[ebeg + i];
            int pos = atomicAdd(&cur[p >> 24], 1);
            srclist[ebeg + pos] = (int)(p & 0xFFFFFFu);
        }
    }
}

// ---------- swizzled B staging via global_load_lds (256 threads) ----------
// [nrows x 64] short plane (global pitch 128) -> LDS pitch 64, 16B chunks XOR-swizzled.
__device__ __forceinline__ void stage_swz(const unsigned short* __restrict__ g,
                                          long rowBase, long maxRow, int kOff,
                                          unsigned short* lds, int nrows, int tid) {
    const int nchunks = nrows << 3;
    for (int L = tid; L < nchunks; L += 256) {
        int r = L >> 3, cS = L & 7;
        int cG = cS ^ (r & 7);
        long gr = rowBase + r;
        if (gr >= maxRow) gr = maxRow - 1;
        gload_lds16(g + gr * HDIM + kOff + cG * 8, lds + (long)L * 8);
    }
}
__device__ __forceinline__ int swz_off(int r, int c0) {
    return (r * 8 + (c0 ^ (r & 7))) * 8;
}

// ---------- FUSED: LSTM + layer-1 transform ----------
// Phase A (R3-proven lstm): gates = z @ W_ih^T + bsum, sequential-gate,
//   double-buffered weight staging with counted vmcnt(8).
// Phase B (fused gemm1): h never goes to HBM; written to LDS buf0 swizzled,
//   W1 staged into buf1, gemm loop emits Tb = bf16(dinv * (h @ W1^T)).
__global__ __launch_bounds__(256, 2)
void lstm_gemm1_fused(const float* __restrict__ Z,
                      const unsigned short* __restrict__ Wh, const unsigned short* __restrict__ Wl,
                      const unsigned short* __restrict__ W1h, const unsigned short* __restrict__ W1l,
                      const float* __restrict__ bsum, const float* __restrict__ dinv,
                      unsigned short* __restrict__ Tb, long M)
{
    __shared__ unsigned short sBh[2][128 * 64], sBl[2][128 * 64];   // 64 KB total
    const int tid = threadIdx.x;
    const long rowBase = (long)blockIdx.x * 64;

    const int wave = tid >> 6;
    const int lane = tid & 63;
    const int quad = lane >> 4;
    const int l16  = lane & 15;
    const int arow = wave * 16 + l16;
    long ag = rowBase + arow;
    if (ag >= M) ag = M - 1;

    // load fp32 z fragments and split to bf16 hi/lo in-register
    short8 rah[2][2], ral[2][2];
#pragma unroll
    for (int h = 0; h < 2; ++h)
#pragma unroll
        for (int kk = 0; kk < 2; ++kk) {
            const float* p = Z + ag * HDIM + h * 64 + kk * 32 + quad * 8;
            float4 f0 = *(const float4*)p;
            float4 f1 = *(const float4*)(p + 4);
            float f[8] = {f0.x, f0.y, f0.z, f0.w, f1.x, f1.y, f1.z, f1.w};
#pragma unroll
            for (int e = 0; e < 8; ++e) {
                unsigned short hi, lo;
                split1(f[e], hi, lo);
                rah[h][kk][e] = (short)hi;
                ral[h][kk][e] = (short)lo;
            }
        }

    // stage one phase-tile (gate g, K-half h) into buffer b: 8 loads/thread.
    auto stage_phase = [&](int ph, int b) {
        const int g = ph >> 1, h = ph & 1;
        const int gateRow = (g == 0) ? 0 : ((g == 1) ? 256 : 384);
        const unsigned short* gh = Wh + (long)gateRow * HDIM + h * 64;
        const unsigned short* gl = Wl + (long)gateRow * HDIM + h * 64;
#pragma unroll
        for (int it = 0; it < 4; ++it) {
            int L = it * 256 + tid;
            int r = L >> 3, cS = L & 7, cG = cS ^ (r & 7);
            gload_lds16(gh + (long)r * HDIM + cG * 8, &sBh[b][L * 8]);
        }
#pragma unroll
        for (int it = 0; it < 4; ++it) {
            int L = it * 256 + tid;
            int r = L >> 3, cS = L & 7, cG = cS ^ (r & 7);
            gload_lds16(gl + (long)r * HDIM + cG * 8, &sBl[b][L * 8]);
        }
    };

    floatx4 acc[8];      // current gate accumulator
    floatx4 st[8];       // persistent cell state across gates
#pragma unroll
    for (int i = 0; i < 8; ++i) acc[i] = (floatx4)0.0f;

    // prologue: stage phase 0 into buffer 0
    stage_phase(0, 0);

    // 6 phases: (gate i: h=0,1), (gate g: h=0,1), (gate o: h=0,1)
#pragma unroll
    for (int ph = 0; ph < 6; ++ph) {
        const int b = ph & 1;
        if (ph < 5) stage_phase(ph + 1, b ^ 1);   // prefetch next tile
        // gate-finish transforms overlap the in-flight staging
        if (ph == 2) {
#pragma unroll
            for (int ct = 0; ct < 8; ++ct) {
                const float bb = bsum[ct * 16 + l16];
#pragma unroll
                for (int r = 0; r < 4; ++r)
                    st[ct][r] = fast_sigmoid(acc[ct][r] + bb);
                acc[ct] = (floatx4)0.0f;
            }
        } else if (ph == 4) {
#pragma unroll
            for (int ct = 0; ct < 8; ++ct) {
                const float bb = bsum[256 + ct * 16 + l16];
#pragma unroll
                for (int r = 0; r < 4; ++r) {
                    float cv = st[ct][r] * fast_tanh(acc[ct][r] + bb);
                    st[ct][r] = fast_tanh(cv);
                }
                acc[ct] = (floatx4)0.0f;
            }
        }
        // wait ONLY for the current buffer's 8 loads; next tile stays in flight
        if (ph < 5) asm volatile("s_waitcnt vmcnt(8)" ::: "memory");
        else        asm volatile("s_waitcnt vmcnt(0)" ::: "memory");
        __builtin_amdgcn_s_barrier();
        asm volatile("" ::: "memory");
        const int hh_ = ph & 1;
#pragma unroll
        for (int kk = 0; kk < 2; ++kk) {
            const int c0 = kk * 4 + quad;
            short8 a_h = rah[hh_][kk];
            short8 a_l = ral[hh_][kk];
#pragma unroll
            for (int ct = 0; ct < 8; ++ct) {
                const int bo = swz_off(ct * 16 + l16, c0);
                short8 bh = *(const short8*)(&sBh[b][0] + bo);
                short8 bl = *(const short8*)(&sBl[b][0] + bo);
                acc[ct] = __builtin_amdgcn_mfma_f32_16x16x32_bf16(a_h, bh, acc[ct], 0, 0, 0);
                acc[ct] = __builtin_amdgcn_mfma_f32_16x16x32_bf16(a_h, bl, acc[ct], 0, 0, 0);
                acc[ct] = __builtin_amdgcn_mfma_f32_16x16x32_bf16(a_l, bh, acc[ct], 0, 0, 0);
            }
        }
        // LDS reads of buffer b done; prefetch vmcnt stays outstanding.
        asm volatile("s_waitcnt lgkmcnt(0)" ::: "memory");
        __builtin_amdgcn_s_barrier();
        asm volatile("" ::: "memory");
    }

    // gate-o epilogue: h = sigmoid(o + b_o) * st  -> write h planes to LDS buf0
#pragma unroll
    for (int ct = 0; ct < 8; ++ct) {
        const float bb = bsum[384 + ct * 16 + l16];
#pragma unroll
        for (int r = 0; r < 4; ++r) {
            float hv = fast_sigmoid(acc[ct][r] + bb) * st[ct][r];
            unsigned short hh, hl;
            split1(hv, hh, hl);
            int row = wave * 16 + quad * 4 + r;      // 0..63 tile-local
            int col = ct * 16 + l16;
            int c = col >> 3;
            int sc = (c & 8) | ((c ^ row) & 7);
            int idx = (row * 16 + sc) * 8 + (col & 7);
            sBh[0][idx] = hh;
            sBl[0][idx] = hl;
        }
    }

    // ---- fused gemm1: Tb = bf16( dinv * (h @ W1^T) ) ----
    floatx4 acc2[8];
#pragma unroll
    for (int i = 0; i < 8; ++i) acc2[i] = (floatx4)0.0f;

#pragma unroll
    for (int h2 = 0; h2 < 2; ++h2) {
        __syncthreads();    // h-writes visible (h2=0) / buf1 reads done (h2=1)
        stage_swz(W1h, 0, 128, h2 * 64, &sBh[1][0], 128, tid);
        stage_swz(W1l, 0, 128, h2 * 64, &sBl[1][0], 128, tid);
        __syncthreads();    // W1 half staged
#pragma unroll
        for (int kk = 0; kk < 2; ++kk) {
            const int cA = h2 * 8 + kk * 4 + quad;
            const int scA = (cA & 8) | ((cA ^ arow) & 7);
            short8 a_h = *(const short8*)(&sBh[0][(arow * 16 + scA) * 8]);
            short8 a_l = *(const short8*)(&sBl[0][(arow * 16 + scA) * 8]);
            const int c0 = kk * 4 + quad;
#pragma unroll
            for (int ct = 0; ct < 8; ++ct) {
                const int bo = swz_off(ct * 16 + l16, c0);
                short8 bh = *(const short8*)(&sBh[1][0] + bo);
                short8 bl = *(const short8*)(&sBl[1][0] + bo);
                acc2[ct] = __builtin_amdgcn_mfma_f32_16x16x32_bf16(a_h, bh, acc2[ct], 0, 0, 0);
                acc2[ct] = __builtin_amdgcn_mfma_f32_16x16x32_bf16(a_h, bl, acc2[ct], 0, 0, 0);
                acc2[ct] = __builtin_amdgcn_mfma_f32_16x16x32_bf16(a_l, bh, acc2[ct], 0, 0, 0);
            }
        }
    }

    // epilogue2: scale by dinv, emit bf16 messages
#pragma unroll
    for (int ct = 0; ct < 8; ++ct) {
#pragma unroll
        for (int r = 0; r < 4; ++r) {
            long m = rowBase + wave * 16 + quad * 4 + r;
            if (m < M) {
                int n = ct * 16 + l16;
                float v = acc2[ct][r] * dinv[m];
                Tb[m * HDIM + n] = f2bf(v);
            }
        }
    }
}

// ---------- FUSED: layer-1 aggregate + layer-2/final-linear transform ----------
// Phase A: each wave aggregates 16 consecutive nodes (gather loop identical to
//   aggregate_kernel); x1 = relu(dinv*sum + b1) written to LDS hi/lo planes in
//   the R10-verified swizzled layout -- x1 never hits HBM.
// Phase B: gemm loop (identical math to gemm_split mode 0) with A from LDS and
//   B = W23 staged via stage_swz; emits Tb2 = bf16(dinv * (x1 @ W23^T)).
// NOTE: output MUST be a different buffer than the message table t (other
//   blocks' phase A still gathers from t concurrently).
__global__ __launch_bounds__(256, 2)
void agg1_gemm2_fused(const unsigned short* __restrict__ t, const int* __restrict__ srclist,
                      const int* __restrict__ offs, const float* __restrict__ dinv,
                      const float* __restrict__ b1,
                      const unsigned short* __restrict__ Bh, const unsigned short* __restrict__ Bl,
                      unsigned short* __restrict__ Tb2, long M)
{
    __shared__ unsigned short sAh[64 * 128], sAl[64 * 128];   // 32 KB: x1 tile
    __shared__ unsigned short sBh[128 * 64], sBl[128 * 64];   // 32 KB: W23 half
    const int tid = threadIdx.x;
    const long rowBase = (long)blockIdx.x * 64;

    const int wave = tid >> 6;
    const int lane = tid & 63;
    const int quad = lane >> 4;
    const int l16  = lane & 15;

    // ---- phase A: aggregate; wave w handles tile rows w*16 .. w*16+15 ----
    const int c = lane * 2;
    for (int i = 0; i < 16; ++i) {
        const int row = wave * 16 + i;
        const long node = rowBase + row;
        float v0 = 0.0f, v1 = 0.0f;
        if (node < M) {
            const int beg = offs[node];
            const int end = offs[node + 1];
            float s0[8], s1[8];
#pragma unroll
            for (int q = 0; q < 8; ++q) { s0[q] = 0.0f; s1[q] = 0.0f; }
            int j = beg;
            for (; j + 8 <= end; j += 8) {
                int srcs[8];
#pragma unroll
                for (int q = 0; q < 8; ++q) srcs[q] = srclist[j + q];
                unsigned int p[8];
#pragma unroll
                for (int q = 0; q < 8; ++q) p[q] = *(const unsigned int*)(t + (long)srcs[q] * HDIM + c);
#pragma unroll
                for (int q = 0; q < 8; ++q) {
                    s0[q] += bf2f((unsigned short)(p[q] & 0xffffu));
                    s1[q] += bf2f((unsigned short)(p[q] >> 16));
                }
            }
            for (; j + 4 <= end; j += 4) {
                int srcs[4];
#pragma unroll
                for (int q = 0; q < 4; ++q) srcs[q] = srclist[j + q];
#pragma unroll
                for (int q = 0; q < 4; ++q) {
                    unsigned int p = *(const unsigned int*)(t + (long)srcs[q] * HDIM + c);
                    s0[q] += bf2f((unsigned short)(p & 0xffffu));
                    s1[q] += bf2f((unsigned short)(p >> 16));
                }
            }
            for (; j < end; ++j) {
                unsigned int p = *(const unsigned int*)(t + (long)srclist[j] * HDIM + c);
                s0[0] += bf2f((unsigned short)(p & 0xffffu));
                s1[0] += bf2f((unsigned short)(p >> 16));
            }
            const unsigned int ps = *(const unsigned int*)(t + node * HDIM + c);
            s0[0] += bf2f((unsigned short)(ps & 0xffffu));    // self-loop
            s1[0] += bf2f((unsigned short)(ps >> 16));
            float a0 = ((s0[0] + s0[1]) + (s0[2] + s0[3])) + ((s0[4] + s0[5]) + (s0[6] + s0[7]));
            float a1 = ((s1[0] + s1[1]) + (s1[2] + s1[3])) + ((s1[4] + s1[5]) + (s1[6] + s1[7]));
            const float d = dinv[node];
            v0 = fmaxf(d * a0 + b1[c], 0.0f);
            v1 = fmaxf(d * a1 + b1[c + 1], 0.0f);
        }
        unsigned short h0, l0, h1, l1;
        split1(v0, h0, l0);
        split1(v1, h1, l1);
        const int ch = c >> 3;
        const int sc = (ch & 8) | ((ch ^ row) & 7);
        const int idx = (row * 16 + sc) * 8 + (c & 7);
        *(unsigned int*)(sAh + idx) = (unsigned int)h0 | ((unsigned int)h1 << 16);
        *(unsigned int*)(sAl + idx) = (unsigned int)l0 | ((unsigned int)l1 << 16);
    }

    // ---- phase B: Tb2 = bf16( dinv * (x1 @ W23^T) ) ----
    const int arow = wave * 16 + l16;
    floatx4 acc2[8];
#pragma unroll
    for (int i = 0; i < 8; ++i) acc2[i] = (floatx4)0.0f;

#pragma unroll
    for (int h2 = 0; h2 < 2; ++h2) {
        __syncthreads();    // phase-A writes visible (h2=0) / sB reads done (h2=1)
        stage_swz(Bh, 0, 128, h2 * 64, sBh, 128, tid);
        stage_swz(Bl, 0, 128, h2 * 64, sBl, 128, tid);
        __syncthreads();    // W23 half staged
#pragma unroll
        for (int kk = 0; kk < 2; ++kk) {
            const int cA = h2 * 8 + kk * 4 + quad;
            const int scA = (cA & 8) | ((cA ^ arow) & 7);
            short8 a_h = *(const short8*)(&sAh[(arow * 16 + scA) * 8]);
            short8 a_l = *(const short8*)(&sAl[(arow * 16 + scA) * 8]);
            const int c0 = kk * 4 + quad;
#pragma unroll
            for (int ct = 0; ct < 8; ++ct) {
                const int bo = swz_off(ct * 16 + l16, c0);
                short8 bh = *(const short8*)(sBh + bo);
                short8 bl = *(const short8*)(sBl + bo);
                acc2[ct] = __builtin_amdgcn_mfma_f32_16x16x32_bf16(a_h, bh, acc2[ct], 0, 0, 0);
                acc2[ct] = __builtin_amdgcn_mfma_f32_16x16x32_bf16(a_h, bl, acc2[ct], 0, 0, 0);
                acc2[ct] = __builtin_amdgcn_mfma_f32_16x16x32_bf16(a_l, bh, acc2[ct], 0, 0, 0);
            }
        }
    }

#pragma unroll
    for (int ct = 0; ct < 8; ++ct) {
#pragma unroll
        for (int r = 0; r < 4; ++r) {
            long m = rowBase + wave * 16 + quad * 4 + r;
            if (m < M) {
                int n = ct * 16 + l16;
                float v = acc2[ct][r] * dinv[m];
                Tb2[m * HDIM + n] = f2bf(v);
            }
        }
    }
}

// ---------- pull aggregation over bf16 messages (unroll 8) ----------
// outF == nullptr: write split planes Xh/Xl (doRelu optional).
// outF != nullptr: write fp32 out with relu (fused layer2+final-linear path).
__global__ __launch_bounds__(256, 4)
void aggregate_kernel(const unsigned short* __restrict__ t, const int* __restrict__ srclist,
                      const int* __restrict__ offs, const float* __restrict__ dinv,
                      const float* __restrict__ bias, int doRelu,
                      unsigned short* __restrict__ Xh, unsigned short* __restrict__ Xl,
                      float* __restrict__ outF, long N)
{
    long node = (long)blockIdx.x * 4 + (threadIdx.x >> 6);
    if (node >= N) return;
    const int lane = threadIdx.x & 63;
    const int c = lane * 2;
    const int beg = offs[node];
    const int end = offs[node + 1];
    float s0[8], s1[8];
#pragma unroll
    for (int q = 0; q < 8; ++q) { s0[q] = 0.0f; s1[q] = 0.0f; }
    int j = beg;
    for (; j + 8 <= end; j += 8) {
        int srcs[8];
#pragma unroll
        for (int q = 0; q < 8; ++q) srcs[q] = srclist[j + q];
        unsigned int p[8];
#pragma unroll
        for (int q = 0; q < 8; ++q) p[q] = *(const unsigned int*)(t + (long)srcs[q] * HDIM + c);
#pragma unroll
        for (int q = 0; q < 8; ++q) {
            s0[q] += bf2f((unsigned short)(p[q] & 0xffffu));
            s1[q] += bf2f((unsigned short)(p[q] >> 16));
        }
    }
    for (; j + 4 <= end; j += 4) {
        int srcs[4];
#pragma unroll
        for (int q = 0; q < 4; ++q) srcs[q] = srclist[j + q];
#pragma unroll
        for (int q = 0; q < 4; ++q) {
            unsigned int p = *(const unsigned int*)(t + (long)srcs[q] * HDIM + c);
            s0[q] += bf2f((unsigned short)(p & 0xffffu));
            s1[q] += bf2f((unsigned short)(p >> 16));
        }
    }
    for (; j < end; ++j) {
        unsigned int p = *(const unsigned int*)(t + (long)srclist[j] * HDIM + c);
        s0[0] += bf2f((unsigned short)(p & 0xffffu));
        s1[0] += bf2f((unsigned short)(p >> 16));
    }
    const unsigned int ps = *(const unsigned int*)(t + node * HDIM + c);
    s0[0] += bf2f((unsigned short)(ps & 0xffffu));    // self-loop
    s1[0] += bf2f((unsigned short)(ps >> 16));
    float a0 = ((s0[0] + s0[1]) + (s0[2] + s0[3])) + ((s0[4] + s0[5]) + (s0[6] + s0[7]));
    float a1 = ((s1[0] + s1[1]) + (s1[2] + s1[3])) + ((s1[4] + s1[5]) + (s1[6] + s1[7]));
    const float d = dinv[node];
    float v0 = d * a0 + bias[c];
    float v1 = d * a1 + bias[c + 1];
    if (outF) {
        v0 = fmaxf(v0, 0.0f);
        v1 = fmaxf(v1, 0.0f);
        float2 o2 = {v0, v1};
        *(float2*)(outF + node * HDIM + c) = o2;
        return;
    }
    if (doRelu) { v0 = fmaxf(v0, 0.0f); v1 = fmaxf(v1, 0.0f); }
    unsigned short h0, l0, h1, l1;
    split1(v0, h0, l0);
    split1(v1, h1, l1);
    *(unsigned int*)(Xh + node * HDIM + c) = (unsigned int)h0 | ((unsigned int)h1 << 16);
    *(unsigned int*)(Xl + node * HDIM + c) = (unsigned int)l0 | ((unsigned int)l1 << 16);
}

extern "C" void kernel_launch(void* const* d_in, const int* in_sizes, int n_in,
                              void* d_out, int out_size, void* d_ws, size_t ws_size,
                              hipStream_t stream)
{
    const float* z   = (const float*)d_in[0];
    const int*   ei  = (const int*)d_in[1];
    const float* Wih = (const float*)d_in[2];
    /* d_in[3] = W_hh: unused (h0 = 0) */
    const float* bih = (const float*)d_in[4];
    const float* bhh = (const float*)d_in[5];
    const float* W1  = (const float*)d_in[6];
    const float* b1  = (const float*)d_in[7];
    const float* W2  = (const float*)d_in[8];
    const float* b2  = (const float*)d_in[9];
    const float* W3  = (const float*)d_in[10];
    const float* b3  = (const float*)d_in[11];
    float* out = (float*)d_out;

    const long N = in_sizes[0] / HDIM;
    const long E = in_sizes[1] / 2;
    const int  K = (int)((N + NPB - 1) / NPB);

    char* ws = (char*)d_ws;
    size_t off = 0;
    auto alloc = [&](size_t bytes) {
        char* p = ws + off;
        off += (bytes + 255) & ~(size_t)255;
        return (void*)p;
    };
    int*   bcnt    = (int*)alloc(K * 4);
    int*   gbase   = (int*)alloc((K + 1) * 4);
    int*   gcur    = (int*)alloc(K * 4);
    int*   offs    = (int*)alloc((N + 1) * 4);
    float* dinv    = (float*)alloc(N * 4);
    unsigned int* pairs = (unsigned int*)alloc(E * 4);
    int*   srclist = (int*)alloc(E * 4);
    unsigned short* Tb  = (unsigned short*)alloc(N * HDIM * 2);  // layer-1 messages
    unsigned short* Tb2 = (unsigned short*)alloc(N * HDIM * 2);  // layer-2 messages
    unsigned short* Wihh = (unsigned short*)alloc(512 * HDIM * 2);
    unsigned short* Wihl = (unsigned short*)alloc(512 * HDIM * 2);
    unsigned short* W1h  = (unsigned short*)alloc(HDIM * HDIM * 2);
    unsigned short* W1l  = (unsigned short*)alloc(HDIM * HDIM * 2);
    unsigned short* W23h = (unsigned short*)alloc(HDIM * HDIM * 2);
    unsigned short* W23l = (unsigned short*)alloc(HDIM * HDIM * 2);
    float* bsum = (float*)alloc(512 * 4);
    float* b23  = (float*)alloc(HDIM * 4);

    const int gblocks  = (int)((N + 63) / 64);
    const int ablocks  = (int)((N + 3) / 4);
    const int cblocks  = (int)((E + CHUNK - 1) / CHUNK);

    // ---- bucketed CSR build ----
    hipMemsetAsync(bcnt, 0, K * 4, stream);
    bucket_hist_kernel<<<cblocks, 256, 0, stream>>>(ei, bcnt, E, K);
    scan_buckets_kernel<<<1, 1024, 0, stream>>>(bcnt, gbase, gcur, offs, K, (int)N, (int)E);
    pair_scatter_kernel<<<cblocks, 256, 0, stream>>>(ei, gcur, pairs, E, K);
    bucket_csr_kernel<<<K, 256, 0, stream>>>(pairs, gbase, offs, dinv, srclist, (int)N);

    // weight prep (Wih split, W1^T split, bsum) + fused W23 = W2@W3^T, b23
    prep_weights_kernel<<<322, 256, 0, stream>>>(Wih, W1, bih, bhh,
                                                 Wihh, Wihl, W1h, W1l, bsum);
    prep_w23_kernel<<<65, 256, 0, stream>>>(W2, W3, b2, b3, W23h, W23l, b23);

    // fused: h = lstm(z); Tb = bf16(dinv * (h @ W1^T))   (h never hits HBM)
    lstm_gemm1_fused<<<gblocks, 256, 0, stream>>>(z, Wihh, Wihl, W1h, W1l,
                                                  bsum, dinv, Tb, N);

    // fused: x1 = relu(A_hat Tb + b1); Tb2 = bf16(dinv * (x1 @ W23^T))
    // (x1 never hits HBM; Tb2 != Tb to avoid racing concurrent gathers)
    agg1_gemm2_fused<<<gblocks, 256, 0, stream>>>(Tb, srclist, offs, dinv, b1,
                                                  W23h, W23l, Tb2, N);

    // final aggregate: out = relu(A_hat Tb2 + b23)
    aggregate_kernel<<<ablocks, 256, 0, stream>>>(Tb2, srclist, offs, dinv, b23, 1,
                                                  nullptr, nullptr, out, N);
}

// Round 12
// 419.930 us; speedup vs baseline: 1.2631x; 1.2631x over previous
//
#include <hip/hip_runtime.h>
#include <math.h>

typedef __attribute__((ext_vector_type(8))) short short8;
typedef __attribute__((ext_vector_type(4))) float floatx4;

#define HDIM 128
#define NPB 256          // nodes per bucket (CSR build)
#define BKMAX 1024       // max buckets (N <= 262144)
#define CHUNK 8192       // edges per pair_scatter block
#define STAGE_CAP 8192   // per-bucket srclist LDS stage (ints)

__device__ __forceinline__ float bf2f(unsigned short u) {
    unsigned int x = ((unsigned int)u) << 16;
    float f;
    __builtin_memcpy(&f, &x, 4);
    return f;
}
__device__ __forceinline__ unsigned short f2bf(float f) {
    unsigned int x;
    __builtin_memcpy(&x, &f, 4);
    unsigned int r = (x + 0x7fffu + ((x >> 16) & 1u)) >> 16;  // RNE
    return (unsigned short)r;
}
// split: hi = truncated bf16 (cheap), lo = RNE bf16 of residual.
__device__ __forceinline__ void split1(float v, unsigned short& hi, unsigned short& lo) {
    unsigned int x;
    __builtin_memcpy(&x, &v, 4);
    hi = (unsigned short)(x >> 16);
    lo = f2bf(v - bf2f(hi));
}
__device__ __forceinline__ float fast_sigmoid(float x) {
    return 1.0f / (1.0f + __expf(-x));
}
__device__ __forceinline__ float fast_tanh(float x) {
    float ax = fabsf(x);
    float e = __expf(2.0f * ax);
    float t = 1.0f - 2.0f / (e + 1.0f);
    return copysignf(t, x);
}

// 16B async global->LDS
__device__ __forceinline__ void gload_lds16(const void* g, void* lds) {
    __builtin_amdgcn_global_load_lds(
        (const __attribute__((address_space(1))) unsigned int*)g,
        (__attribute__((address_space(3))) unsigned int*)lds, 16, 0, 0);
}

// ---------- fused weight prep ----------
// [0,65536) Wih split | [65536,81920) W1^T split | [81920,82432) bsum
__global__ void prep_weights_kernel(const float* __restrict__ Wih,
                                    const float* __restrict__ W1,
                                    const float* __restrict__ bih,
                                    const float* __restrict__ bhh,
                                    unsigned short* __restrict__ Wihh, unsigned short* __restrict__ Wihl,
                                    unsigned short* __restrict__ W1h,  unsigned short* __restrict__ W1l,
                                    float* __restrict__ bsum) {
    int i = blockIdx.x * 256 + threadIdx.x;
    unsigned short h, l;
    if (i < 65536) {
        split1(Wih[i], h, l);
        Wihh[i] = h; Wihl[i] = l;
    } else if (i < 81920) {
        int t = i - 65536, r = t >> 7, c = t & 127;
        split1(W1[r * HDIM + c], h, l);
        W1h[c * HDIM + r] = h; W1l[c * HDIM + r] = l;
    } else if (i < 82432) {
        int t = i - 81920;
        bsum[t] = bih[t] + bhh[t];
    }
}

// ---------- fused W23 = W2 @ W3^T prep (layer-2 GCN x final Linear fusion) ----
// out = relu((A_hat(x1 W2)+b2)W3^T + b3) = relu(A_hat(x1 (W2 W3^T)) + (b2 W3^T + b3))
// B-layout: B[n][k] = sum_p W2[k][p] * W3[n][p].
// [0,16384): W23 split planes; [16384,16512): b23[n] = b3[n] + sum_p b2[p]*W3[n][p]
__global__ void prep_w23_kernel(const float* __restrict__ W2,
                                const float* __restrict__ W3,
                                const float* __restrict__ b2,
                                const float* __restrict__ b3,
                                unsigned short* __restrict__ W23h,
                                unsigned short* __restrict__ W23l,
                                float* __restrict__ b23) {
    int i = blockIdx.x * 256 + threadIdx.x;
    if (i < 16384) {
        int n = i >> 7, k = i & 127;
        float s = 0.0f;
#pragma unroll 8
        for (int p = 0; p < 128; ++p)
            s += W2[k * HDIM + p] * W3[n * HDIM + p];
        unsigned short h, l;
        split1(s, h, l);
        W23h[n * HDIM + k] = h;
        W23l[n * HDIM + k] = l;
    } else if (i < 16512) {
        int n = i - 16384;
        float s = b3[n];
#pragma unroll 8
        for (int p = 0; p < 128; ++p)
            s += b2[p] * W3[n * HDIM + p];
        b23[n] = s;
    }
}

// ================= bucketed CSR build =================
__global__ __launch_bounds__(256)
void bucket_hist_kernel(const int* __restrict__ ei, int* __restrict__ bcnt,
                        long E, int K) {
    __shared__ int h[BKMAX];
    const int tid = threadIdx.x;
    for (int i = tid; i < K; i += 256) h[i] = 0;
    __syncthreads();
    const long base = (long)blockIdx.x * CHUNK;
#pragma unroll
    for (int j = 0; j < CHUNK / 256; ++j) {
        long e = base + j * 256 + tid;
        if (e < E) atomicAdd(&h[((unsigned)ei[E + e]) >> 8], 1);
    }
    __syncthreads();
    for (int i = tid; i < K; i += 256) {
        int c = h[i];
        if (c) atomicAdd(&bcnt[i], c);
    }
}

__global__ __launch_bounds__(1024)
void scan_buckets_kernel(const int* __restrict__ bcnt, int* __restrict__ gbase,
                         int* __restrict__ gcur, int* __restrict__ offs,
                         int K, int N, int Etot) {
    __shared__ int buf[1024];
    const int t = threadIdx.x;
    const int v = (t < K) ? bcnt[t] : 0;
    buf[t] = v;
    __syncthreads();
    for (int off = 1; off < 1024; off <<= 1) {
        int x = buf[t];
        int y = (t >= off) ? buf[t - off] : 0;
        __syncthreads();
        buf[t] = x + y;
        __syncthreads();
    }
    if (t < K) { gbase[t] = buf[t] - v; gcur[t] = buf[t] - v; }
    if (t == 0) { gbase[K] = Etot; offs[N] = Etot; }
}

__global__ __launch_bounds__(256)
void pair_scatter_kernel(const int* __restrict__ ei, int* __restrict__ gcur,
                         unsigned int* __restrict__ pairs, long E, int K) {
    __shared__ int h[BKMAX];
    __shared__ int cur[BKMAX];
    const int tid = threadIdx.x;
    for (int i = tid; i < K; i += 256) h[i] = 0;
    __syncthreads();
    const long base = (long)blockIdx.x * CHUNK;
#pragma unroll
    for (int j = 0; j < CHUNK / 256; ++j) {
        long e = base + j * 256 + tid;
        if (e < E) atomicAdd(&h[((unsigned)ei[E + e]) >> 8], 1);
    }
    __syncthreads();
    for (int i = tid; i < K; i += 256) {
        int c = h[i];
        cur[i] = c ? atomicAdd(&gcur[i], c) : 0;
    }
    __syncthreads();
#pragma unroll
    for (int j = 0; j < CHUNK / 256; ++j) {
        long e = base + j * 256 + tid;
        if (e < E) {
            unsigned int s = (unsigned int)ei[e];
            unsigned int d = (unsigned int)ei[E + e];
            int b = d >> 8;
            int pos = atomicAdd(&cur[b], 1);
            pairs[pos] = s | ((d & (NPB - 1)) << 24);
        }
    }
}

__global__ __launch_bounds__(256)
void bucket_csr_kernel(const unsigned int* __restrict__ pairs, const int* __restrict__ gbase,
                       int* __restrict__ offs, float* __restrict__ dinv,
                       int* __restrict__ srclist, int N) {
    __shared__ int cnt[NPB];
    __shared__ int red[NPB];
    __shared__ int cur[NPB];
    __shared__ int stage[STAGE_CAP];
    const int tid = threadIdx.x;
    const int b = blockIdx.x;
    const int node0 = b << 8;
    const int nn = min(NPB, N - node0);
    const int ebeg = gbase[b];
    const int eend = gbase[b + 1];
    const int ne = eend - ebeg;

    cnt[tid] = 0;
    __syncthreads();
    for (int i = tid; i < ne; i += 256)
        atomicAdd(&cnt[pairs[ebeg + i] >> 24], 1);
    __syncthreads();
    const int myc = cnt[tid];
    red[tid] = myc;
    __syncthreads();
    for (int off = 1; off < NPB; off <<= 1) {
        int x = red[tid];
        int y = (tid >= off) ? red[tid - off] : 0;
        __syncthreads();
        red[tid] = x + y;
        __syncthreads();
    }
    const int loff = red[tid] - myc;   // exclusive
    if (tid < nn) {
        offs[node0 + tid] = ebeg + loff;
        dinv[node0 + tid] = rsqrtf((float)myc + 1.0f);   // +1 self-loop
    }
    cur[tid] = loff;
    __syncthreads();

    if (ne <= STAGE_CAP) {
        for (int i = tid; i < ne; i += 256) {
            unsigned int p = pairs[ebeg + i];
            int pos = atomicAdd(&cur[p >> 24], 1);
            stage[pos] = (int)(p & 0xFFFFFFu);
        }
        __syncthreads();
        for (int i = tid; i < ne; i += 256)
            srclist[ebeg + i] = stage[i];
    } else {
        for (int i = tid; i < ne; i += 256) {
            unsigned int p = pairs[ebeg + i];
            int pos = atomicAdd(&cur[p >> 24], 1);
            srclist[ebeg + pos] = (int)(p & 0xFFFFFFu);
        }
    }
}

// ---------- swizzled B staging via global_load_lds (256 threads) ----------
// [nrows x 64] short plane (global pitch 128) -> LDS pitch 64, 16B chunks XOR-swizzled.
__device__ __forceinline__ void stage_swz(const unsigned short* __restrict__ g,
                                          long rowBase, long maxRow, int kOff,
                                          unsigned short* lds, int nrows, int tid) {
    const int nchunks = nrows << 3;
    for (int L = tid; L < nchunks; L += 256) {
        int r = L >> 3, cS = L & 7;
        int cG = cS ^ (r & 7);
        long gr = rowBase + r;
        if (gr >= maxRow) gr = maxRow - 1;
        gload_lds16(g + gr * HDIM + kOff + cG * 8, lds + (long)L * 8);
    }
}
__device__ __forceinline__ int swz_off(int r, int c0) {
    return (r * 8 + (c0 ^ (r & 7))) * 8;
}

// ---------- split-bf16 GEMM, register-resident A ----------
// C[m,n] = sum_k A[m,k]*B[n,k], 64-row M tile, K=128. A planes read global->VGPR.
// mode 0: outb = bf16( C * rowScale[m] );  mode 1: outf = relu(C + bias[n])
__global__ __launch_bounds__(256, 4)
void gemm_split(const unsigned short* __restrict__ Ah, const unsigned short* __restrict__ Al,
                const unsigned short* __restrict__ Bh, const unsigned short* __restrict__ Bl,
                float* __restrict__ outf, unsigned short* __restrict__ outb, long M,
                const float* __restrict__ rowScale,
                const float* __restrict__ bias, int mode)
{
    __shared__ unsigned short sBh[128 * 64], sBl[128 * 64];
    const int tid = threadIdx.x;
    const long rowBase = (long)blockIdx.x * 64;

    const int wave = tid >> 6;
    const int lane = tid & 63;
    const int quad = lane >> 4;
    const int l16  = lane & 15;
    const int arow = wave * 16 + l16;
    long ag = rowBase + arow;
    if (ag >= M) ag = M - 1;

    // A fragments: [h][kk], hi+lo planes, 16B contiguous per position
    short8 rah[2][2], ral[2][2];
#pragma unroll
    for (int h = 0; h < 2; ++h)
#pragma unroll
        for (int kk = 0; kk < 2; ++kk) {
            const long o = ag * HDIM + h * 64 + kk * 32 + quad * 8;
            rah[h][kk] = *(const short8*)(Ah + o);
            ral[h][kk] = *(const short8*)(Al + o);
        }

    floatx4 acc[8];
#pragma unroll
    for (int i = 0; i < 8; ++i) acc[i] = (floatx4)0.0f;

    for (int h = 0; h < 2; ++h) {
        __syncthreads();
        stage_swz(Bh, 0, 128, h * 64, sBh, 128, tid);
        stage_swz(Bl, 0, 128, h * 64, sBl, 128, tid);
        __syncthreads();
#pragma unroll
        for (int kk = 0; kk < 2; ++kk) {
            const int c0 = kk * 4 + quad;
            short8 ah = rah[h][kk];
            short8 al = ral[h][kk];
#pragma unroll
            for (int ct = 0; ct < 8; ++ct) {
                const int bo = swz_off(ct * 16 + l16, c0);
                short8 bh = *(const short8*)(sBh + bo);
                short8 bl = *(const short8*)(sBl + bo);
                acc[ct] = __builtin_amdgcn_mfma_f32_16x16x32_bf16(ah, bh, acc[ct], 0, 0, 0);
                acc[ct] = __builtin_amdgcn_mfma_f32_16x16x32_bf16(ah, bl, acc[ct], 0, 0, 0);
                acc[ct] = __builtin_amdgcn_mfma_f32_16x16x32_bf16(al, bh, acc[ct], 0, 0, 0);
            }
        }
    }

#pragma unroll
    for (int ct = 0; ct < 8; ++ct) {
#pragma unroll
        for (int r = 0; r < 4; ++r) {
            long m = rowBase + wave * 16 + quad * 4 + r;
            if (m < M) {
                int n = ct * 16 + l16;
                float v = acc[ct][r];
                if (mode == 0) {
                    v *= rowScale[m];
                    outb[m * HDIM + n] = f2bf(v);
                } else {
                    v += bias[n];
                    v = fmaxf(v, 0.0f);
                    outf[m * HDIM + n] = v;
                }
            }
        }
    }
}

// ---------- FUSED: LSTM + layer-1 transform ----------
// Phase A (R3-proven lstm): gates = z @ W_ih^T + bsum, sequential-gate,
//   double-buffered weight staging with counted vmcnt(8).
// Phase B (fused gemm1): h never goes to HBM; written to LDS buf0 swizzled,
//   W1 staged into buf1, gemm loop emits Tb = bf16(dinv * (h @ W1^T)).
__global__ __launch_bounds__(256, 2)
void lstm_gemm1_fused(const float* __restrict__ Z,
                      const unsigned short* __restrict__ Wh, const unsigned short* __restrict__ Wl,
                      const unsigned short* __restrict__ W1h, const unsigned short* __restrict__ W1l,
                      const float* __restrict__ bsum, const float* __restrict__ dinv,
                      unsigned short* __restrict__ Tb, long M)
{
    __shared__ unsigned short sBh[2][128 * 64], sBl[2][128 * 64];   // 64 KB total
    const int tid = threadIdx.x;
    const long rowBase = (long)blockIdx.x * 64;

    const int wave = tid >> 6;
    const int lane = tid & 63;
    const int quad = lane >> 4;
    const int l16  = lane & 15;
    const int arow = wave * 16 + l16;
    long ag = rowBase + arow;
    if (ag >= M) ag = M - 1;

    // load fp32 z fragments and split to bf16 hi/lo in-register
    short8 rah[2][2], ral[2][2];
#pragma unroll
    for (int h = 0; h < 2; ++h)
#pragma unroll
        for (int kk = 0; kk < 2; ++kk) {
            const float* p = Z + ag * HDIM + h * 64 + kk * 32 + quad * 8;
            float4 f0 = *(const float4*)p;
            float4 f1 = *(const float4*)(p + 4);
            float f[8] = {f0.x, f0.y, f0.z, f0.w, f1.x, f1.y, f1.z, f1.w};
#pragma unroll
            for (int e = 0; e < 8; ++e) {
                unsigned short hi, lo;
                split1(f[e], hi, lo);
                rah[h][kk][e] = (short)hi;
                ral[h][kk][e] = (short)lo;
            }
        }

    // stage one phase-tile (gate g, K-half h) into buffer b: 8 loads/thread.
    auto stage_phase = [&](int ph, int b) {
        const int g = ph >> 1, h = ph & 1;
        const int gateRow = (g == 0) ? 0 : ((g == 1) ? 256 : 384);
        const unsigned short* gh = Wh + (long)gateRow * HDIM + h * 64;
        const unsigned short* gl = Wl + (long)gateRow * HDIM + h * 64;
#pragma unroll
        for (int it = 0; it < 4; ++it) {
            int L = it * 256 + tid;
            int r = L >> 3, cS = L & 7, cG = cS ^ (r & 7);
            gload_lds16(gh + (long)r * HDIM + cG * 8, &sBh[b][L * 8]);
        }
#pragma unroll
        for (int it = 0; it < 4; ++it) {
            int L = it * 256 + tid;
            int r = L >> 3, cS = L & 7, cG = cS ^ (r & 7);
            gload_lds16(gl + (long)r * HDIM + cG * 8, &sBl[b][L * 8]);
        }
    };

    floatx4 acc[8];      // current gate accumulator
    floatx4 st[8];       // persistent cell state across gates
#pragma unroll
    for (int i = 0; i < 8; ++i) acc[i] = (floatx4)0.0f;

    // prologue: stage phase 0 into buffer 0
    stage_phase(0, 0);

    // 6 phases: (gate i: h=0,1), (gate g: h=0,1), (gate o: h=0,1)
#pragma unroll
    for (int ph = 0; ph < 6; ++ph) {
        const int b = ph & 1;
        if (ph < 5) stage_phase(ph + 1, b ^ 1);   // prefetch next tile
        // gate-finish transforms overlap the in-flight staging
        if (ph == 2) {
#pragma unroll
            for (int ct = 0; ct < 8; ++ct) {
                const float bb = bsum[ct * 16 + l16];
#pragma unroll
                for (int r = 0; r < 4; ++r)
                    st[ct][r] = fast_sigmoid(acc[ct][r] + bb);
                acc[ct] = (floatx4)0.0f;
            }
        } else if (ph == 4) {
#pragma unroll
            for (int ct = 0; ct < 8; ++ct) {
                const float bb = bsum[256 + ct * 16 + l16];
#pragma unroll
                for (int r = 0; r < 4; ++r) {
                    float cv = st[ct][r] * fast_tanh(acc[ct][r] + bb);
                    st[ct][r] = fast_tanh(cv);
                }
                acc[ct] = (floatx4)0.0f;
            }
        }
        // wait ONLY for the current buffer's 8 loads; next tile stays in flight
        if (ph < 5) asm volatile("s_waitcnt vmcnt(8)" ::: "memory");
        else        asm volatile("s_waitcnt vmcnt(0)" ::: "memory");
        __builtin_amdgcn_s_barrier();
        asm volatile("" ::: "memory");
        const int hh_ = ph & 1;
#pragma unroll
        for (int kk = 0; kk < 2; ++kk) {
            const int c0 = kk * 4 + quad;
            short8 a_h = rah[hh_][kk];
            short8 a_l = ral[hh_][kk];
#pragma unroll
            for (int ct = 0; ct < 8; ++ct) {
                const int bo = swz_off(ct * 16 + l16, c0);
                short8 bh = *(const short8*)(&sBh[b][0] + bo);
                short8 bl = *(const short8*)(&sBl[b][0] + bo);
                acc[ct] = __builtin_amdgcn_mfma_f32_16x16x32_bf16(a_h, bh, acc[ct], 0, 0, 0);
                acc[ct] = __builtin_amdgcn_mfma_f32_16x16x32_bf16(a_h, bl, acc[ct], 0, 0, 0);
                acc[ct] = __builtin_amdgcn_mfma_f32_16x16x32_bf16(a_l, bh, acc[ct], 0, 0, 0);
            }
        }
        // LDS reads of buffer b done; prefetch vmcnt stays outstanding.
        asm volatile("s_waitcnt lgkmcnt(0)" ::: "memory");
        __builtin_amdgcn_s_barrier();
        asm volatile("" ::: "memory");
    }

    // gate-o epilogue: h = sigmoid(o + b_o) * st  -> write h planes to LDS buf0
#pragma unroll
    for (int ct = 0; ct < 8; ++ct) {
        const float bb = bsum[384 + ct * 16 + l16];
#pragma unroll
        for (int r = 0; r < 4; ++r) {
            float hv = fast_sigmoid(acc[ct][r] + bb) * st[ct][r];
            unsigned short hh, hl;
            split1(hv, hh, hl);
            int row = wave * 16 + quad * 4 + r;      // 0..63 tile-local
            int col = ct * 16 + l16;
            int c = col >> 3;
            int sc = (c & 8) | ((c ^ row) & 7);
            int idx = (row * 16 + sc) * 8 + (col & 7);
            sBh[0][idx] = hh;
            sBl[0][idx] = hl;
        }
    }

    // ---- fused gemm1: Tb = bf16( dinv * (h @ W1^T) ) ----
    floatx4 acc2[8];
#pragma unroll
    for (int i = 0; i < 8; ++i) acc2[i] = (floatx4)0.0f;

#pragma unroll
    for (int h2 = 0; h2 < 2; ++h2) {
        __syncthreads();    // h-writes visible (h2=0) / buf1 reads done (h2=1)
        stage_swz(W1h, 0, 128, h2 * 64, &sBh[1][0], 128, tid);
        stage_swz(W1l, 0, 128, h2 * 64, &sBl[1][0], 128, tid);
        __syncthreads();    // W1 half staged
#pragma unroll
        for (int kk = 0; kk < 2; ++kk) {
            const int cA = h2 * 8 + kk * 4 + quad;
            const int scA = (cA & 8) | ((cA ^ arow) & 7);
            short8 a_h = *(const short8*)(&sBh[0][(arow * 16 + scA) * 8]);
            short8 a_l = *(const short8*)(&sBl[0][(arow * 16 + scA) * 8]);
            const int c0 = kk * 4 + quad;
#pragma unroll
            for (int ct = 0; ct < 8; ++ct) {
                const int bo = swz_off(ct * 16 + l16, c0);
                short8 bh = *(const short8*)(&sBh[1][0] + bo);
                short8 bl = *(const short8*)(&sBl[1][0] + bo);
                acc2[ct] = __builtin_amdgcn_mfma_f32_16x16x32_bf16(a_h, bh, acc2[ct], 0, 0, 0);
                acc2[ct] = __builtin_amdgcn_mfma_f32_16x16x32_bf16(a_h, bl, acc2[ct], 0, 0, 0);
                acc2[ct] = __builtin_amdgcn_mfma_f32_16x16x32_bf16(a_l, bh, acc2[ct], 0, 0, 0);
            }
        }
    }

    // epilogue2: scale by dinv, emit bf16 messages
#pragma unroll
    for (int ct = 0; ct < 8; ++ct) {
#pragma unroll
        for (int r = 0; r < 4; ++r) {
            long m = rowBase + wave * 16 + quad * 4 + r;
            if (m < M) {
                int n = ct * 16 + l16;
                float v = acc2[ct][r] * dinv[m];
                Tb[m * HDIM + n] = f2bf(v);
            }
        }
    }
}

// ---------- pull aggregation over bf16 messages (unroll 8) ----------
// outF == nullptr: write split planes Xh/Xl (doRelu optional).
// outF != nullptr: write fp32 out with relu (fused layer2+final-linear path).
// launch_bounds (256, 8): gather is latency-bound at 12% HBM BW (R11 PMC);
// 8 blocks/CU doubles waves/CU 16->32 -> 2x outstanding gathers.
__global__ __launch_bounds__(256, 8)
void aggregate_kernel(const unsigned short* __restrict__ t, const int* __restrict__ srclist,
                      const int* __restrict__ offs, const float* __restrict__ dinv,
                      const float* __restrict__ bias, int doRelu,
                      unsigned short* __restrict__ Xh, unsigned short* __restrict__ Xl,
                      float* __restrict__ outF, long N)
{
    long node = (long)blockIdx.x * 4 + (threadIdx.x >> 6);
    if (node >= N) return;
    const int lane = threadIdx.x & 63;
    const int c = lane * 2;
    const int beg = offs[node];
    const int end = offs[node + 1];
    float s0[8], s1[8];
#pragma unroll
    for (int q = 0; q < 8; ++q) { s0[q] = 0.0f; s1[q] = 0.0f; }
    int j = beg;
    for (; j + 8 <= end; j += 8) {
        int srcs[8];
#pragma unroll
        for (int q = 0; q < 8; ++q) srcs[q] = srclist[j + q];
        unsigned int p[8];
#pragma unroll
        for (int q = 0; q < 8; ++q) p[q] = *(const unsigned int*)(t + (long)srcs[q] * HDIM + c);
#pragma unroll
        for (int q = 0; q < 8; ++q) {
            s0[q] += bf2f((unsigned short)(p[q] & 0xffffu));
            s1[q] += bf2f((unsigned short)(p[q] >> 16));
        }
    }
    for (; j + 4 <= end; j += 4) {
        int srcs[4];
#pragma unroll
        for (int q = 0; q < 4; ++q) srcs[q] = srclist[j + q];
#pragma unroll
        for (int q = 0; q < 4; ++q) {
            unsigned int p = *(const unsigned int*)(t + (long)srcs[q] * HDIM + c);
            s0[q] += bf2f((unsigned short)(p & 0xffffu));
            s1[q] += bf2f((unsigned short)(p >> 16));
        }
    }
    for (; j < end; ++j) {
        unsigned int p = *(const unsigned int*)(t + (long)srclist[j] * HDIM + c);
        s0[0] += bf2f((unsigned short)(p & 0xffffu));
        s1[0] += bf2f((unsigned short)(p >> 16));
    }
    const unsigned int ps = *(const unsigned int*)(t + node * HDIM + c);
    s0[0] += bf2f((unsigned short)(ps & 0xffffu));    // self-loop
    s1[0] += bf2f((unsigned short)(ps >> 16));
    float a0 = ((s0[0] + s0[1]) + (s0[2] + s0[3])) + ((s0[4] + s0[5]) + (s0[6] + s0[7]));
    float a1 = ((s1[0] + s1[1]) + (s1[2] + s1[3])) + ((s1[4] + s1[5]) + (s1[6] + s1[7]));
    const float d = dinv[node];
    float v0 = d * a0 + bias[c];
    float v1 = d * a1 + bias[c + 1];
    if (outF) {
        v0 = fmaxf(v0, 0.0f);
        v1 = fmaxf(v1, 0.0f);
        float2 o2 = {v0, v1};
        *(float2*)(outF + node * HDIM + c) = o2;
        return;
    }
    if (doRelu) { v0 = fmaxf(v0, 0.0f); v1 = fmaxf(v1, 0.0f); }
    unsigned short h0, l0, h1, l1;
    split1(v0, h0, l0);
    split1(v1, h1, l1);
    *(unsigned int*)(Xh + node * HDIM + c) = (unsigned int)h0 | ((unsigned int)h1 << 16);
    *(unsigned int*)(Xl + node * HDIM + c) = (unsigned int)l0 | ((unsigned int)l1 << 16);
}

extern "C" void kernel_launch(void* const* d_in, const int* in_sizes, int n_in,
                              void* d_out, int out_size, void* d_ws, size_t ws_size,
                              hipStream_t stream)
{
    const float* z   = (const float*)d_in[0];
    const int*   ei  = (const int*)d_in[1];
    const float* Wih = (const float*)d_in[2];
    /* d_in[3] = W_hh: unused (h0 = 0) */
    const float* bih = (const float*)d_in[4];
    const float* bhh = (const float*)d_in[5];
    const float* W1  = (const float*)d_in[6];
    const float* b1  = (const float*)d_in[7];
    const float* W2  = (const float*)d_in[8];
    const float* b2  = (const float*)d_in[9];
    const float* W3  = (const float*)d_in[10];
    const float* b3  = (const float*)d_in[11];
    float* out = (float*)d_out;

    const long N = in_sizes[0] / HDIM;
    const long E = in_sizes[1] / 2;
    const int  K = (int)((N + NPB - 1) / NPB);

    char* ws = (char*)d_ws;
    size_t off = 0;
    auto alloc = [&](size_t bytes) {
        char* p = ws + off;
        off += (bytes + 255) & ~(size_t)255;
        return (void*)p;
    };
    int*   bcnt    = (int*)alloc(K * 4);
    int*   gbase   = (int*)alloc((K + 1) * 4);
    int*   gcur    = (int*)alloc(K * 4);
    int*   offs    = (int*)alloc((N + 1) * 4);
    float* dinv    = (float*)alloc(N * 4);
    unsigned int* pairs = (unsigned int*)alloc(E * 4);
    int*   srclist = (int*)alloc(E * 4);
    unsigned short* P1h = (unsigned short*)alloc(N * HDIM * 2);  // x1 planes
    unsigned short* P1l = (unsigned short*)alloc(N * HDIM * 2);
    unsigned short* Tb  = (unsigned short*)alloc(N * HDIM * 2);  // scaled messages (bf16)
    unsigned short* Wihh = (unsigned short*)alloc(512 * HDIM * 2);
    unsigned short* Wihl = (unsigned short*)alloc(512 * HDIM * 2);
    unsigned short* W1h  = (unsigned short*)alloc(HDIM * HDIM * 2);
    unsigned short* W1l  = (unsigned short*)alloc(HDIM * HDIM * 2);
    unsigned short* W23h = (unsigned short*)alloc(HDIM * HDIM * 2);
    unsigned short* W23l = (unsigned short*)alloc(HDIM * HDIM * 2);
    float* bsum = (float*)alloc(512 * 4);
    float* b23  = (float*)alloc(HDIM * 4);

    const int gblocks  = (int)((N + 63) / 64);
    const int ablocks  = (int)((N + 3) / 4);
    const int cblocks  = (int)((E + CHUNK - 1) / CHUNK);

    // ---- bucketed CSR build ----
    hipMemsetAsync(bcnt, 0, K * 4, stream);
    bucket_hist_kernel<<<cblocks, 256, 0, stream>>>(ei, bcnt, E, K);
    scan_buckets_kernel<<<1, 1024, 0, stream>>>(bcnt, gbase, gcur, offs, K, (int)N, (int)E);
    pair_scatter_kernel<<<cblocks, 256, 0, stream>>>(ei, gcur, pairs, E, K);
    bucket_csr_kernel<<<K, 256, 0, stream>>>(pairs, gbase, offs, dinv, srclist, (int)N);

    // weight prep (Wih split, W1^T split, bsum) + fused W23 = W2@W3^T, b23
    prep_weights_kernel<<<322, 256, 0, stream>>>(Wih, W1, bih, bhh,
                                                 Wihh, Wihl, W1h, W1l, bsum);
    prep_w23_kernel<<<65, 256, 0, stream>>>(W2, W3, b2, b3, W23h, W23l, b23);

    // fused: h = lstm(z); Tb = bf16(dinv * (h @ W1^T))   (h never hits HBM)
    lstm_gemm1_fused<<<gblocks, 256, 0, stream>>>(z, Wihh, Wihl, W1h, W1l,
                                                  bsum, dinv, Tb, N);

    // layer 1 aggregate: x1 = relu(A_hat Tb + b1) -> P1 planes
    aggregate_kernel<<<ablocks, 256, 0, stream>>>(Tb, srclist, offs, dinv, b1, 1,
                                                  P1h, P1l, nullptr, N);

    // fused layer 2 + final linear: out = relu(A_hat (x1 W23) + b23)
    gemm_split<<<gblocks, 256, 0, stream>>>(P1h, P1l, W23h, W23l, nullptr, Tb, N, dinv, nullptr, 0);
    aggregate_kernel<<<ablocks, 256, 0, stream>>>(Tb, srclist, offs, dinv, b23, 1,
                                                  nullptr, nullptr, out, N);
}